// Round 3
// baseline (34916.782 us; speedup 1.0000x reference)
//
#include <hip/hip_runtime.h>
#include <hip/hip_bf16.h>

// ---------------------------------------------------------------------------
// SimpleCNN / TRM forward. Round 3: persistent-kernel recursion.
// Round-2 finding: 677 dependent small launches cost ~25-40us each (dispatch +
// inter-kernel coherency), dominating the 20.8ms. Fix: ONE persistent kernel
// (grid 256 = #CUs, co-resident) runs all 336 backbone steps (672 GEMMs) with
// software grid barriers; K-loop double-buffers global->reg->LDS staging.
// Math identical to round 2: split-bf16 MFMA (hi+lo), fp32 prologue.
// ---------------------------------------------------------------------------

typedef unsigned short ushort_t;
typedef __attribute__((ext_vector_type(8))) short short8;
typedef __attribute__((ext_vector_type(4))) float f32x4;

__device__ inline unsigned f2bf_rne(float v) {
    unsigned u = __float_as_uint(v);
    return (u + 0x7fffu + ((u >> 16) & 1u)) >> 16;
}
__device__ inline void split2(float v, ushort_t& h, ushort_t& l) {
    unsigned uh = f2bf_rne(v);
    h = (ushort_t)uh;
    float fh = __uint_as_float(uh << 16);
    l = (ushort_t)f2bf_rne(v - fh);
}

// ---------------- conv1 (1->16, 3x3 SAME, 28x28) + relu + maxpool2 ----------
__global__ __launch_bounds__(256) void conv1_pool(
    const float* __restrict__ in, const float* __restrict__ w,
    const float* __restrict__ bias, float* __restrict__ out)
{
    int idx = blockIdx.x * 256 + threadIdx.x;   // 1024*16*14*14
    int xo = idx % 14; int t = idx / 14;
    int yo = t % 14;  t /= 14;
    int oc = t % 16;  int b = t / 16;
    const float* ip = in + (size_t)b * 784;
    const float* wp = w + oc * 9;
    float win[4][4];
#pragma unroll
    for (int yy = 0; yy < 4; ++yy)
#pragma unroll
        for (int xx = 0; xx < 4; ++xx) {
            int y = 2 * yo + yy - 1, x = 2 * xo + xx - 1;
            win[yy][xx] = (y >= 0 && y < 28 && x >= 0 && x < 28) ? ip[y * 28 + x] : 0.f;
        }
    float bs = bias[oc];
    float m = -1e30f;
#pragma unroll
    for (int py = 0; py < 2; ++py)
#pragma unroll
        for (int px = 0; px < 2; ++px) {
            float s = bs;
#pragma unroll
            for (int dy = 0; dy < 3; ++dy)
#pragma unroll
                for (int dx = 0; dx < 3; ++dx)
                    s = fmaf(win[py + dy][px + dx], wp[dy * 3 + dx], s);
            m = fmaxf(m, s);
        }
    out[idx] = fmaxf(m, 0.f);
}

// ---------------- conv2 (16->32, 3x3 SAME, 14x14) + relu + maxpool2 ---------
__global__ __launch_bounds__(256) void conv2_pool(
    const float* __restrict__ in, const float* __restrict__ w,
    const float* __restrict__ bias, float* __restrict__ out)
{
    __shared__ float ws_[32 * 16 * 9];
    for (int i = threadIdx.x; i < 4608; i += 256) ws_[i] = w[i];
    __syncthreads();
    int idx = blockIdx.x * 256 + threadIdx.x;   // 1024*32*7*7
    int xo = idx % 7; int t = idx / 7;
    int yo = t % 7;  t /= 7;
    int oc = t % 32; int b = t / 32;
    const float* ip = in + (size_t)b * 16 * 196;
    float bs = bias[oc];
    float s00 = bs, s01 = bs, s10 = bs, s11 = bs;
    for (int ic = 0; ic < 16; ++ic) {
        const float* ipp = ip + ic * 196;
        float win[4][4];
#pragma unroll
        for (int yy = 0; yy < 4; ++yy)
#pragma unroll
            for (int xx = 0; xx < 4; ++xx) {
                int y = 2 * yo + yy - 1, x = 2 * xo + xx - 1;
                win[yy][xx] = (y >= 0 && y < 14 && x >= 0 && x < 14) ? ipp[y * 14 + x] : 0.f;
            }
        const float* wp = ws_ + (oc * 16 + ic) * 9;
#pragma unroll
        for (int dy = 0; dy < 3; ++dy)
#pragma unroll
            for (int dx = 0; dx < 3; ++dx) {
                float wv = wp[dy * 3 + dx];
                s00 = fmaf(win[0 + dy][0 + dx], wv, s00);
                s01 = fmaf(win[0 + dy][1 + dx], wv, s01);
                s10 = fmaf(win[1 + dy][0 + dx], wv, s10);
                s11 = fmaf(win[1 + dy][1 + dx], wv, s11);
            }
    }
    float m = fmaxf(fmaxf(s00, s01), fmaxf(s10, s11));
    out[idx] = fmaxf(m, 0.f);
}

// ---------------- fp32 tiled GEMM (prologue only: proj1, proj2) -------------
#define BMF 64
#define BNF 64
#define BKF 16

__global__ __launch_bounds__(256) void gemm_f32(
    const float* __restrict__ A0, const float* __restrict__ W,
    const float* __restrict__ bias, float* __restrict__ C,
    int M, int N, int K)
{
    __shared__ float As[BKF][BMF];
    __shared__ float Bs[BKF][BNF];
    const int tid = threadIdx.x;
    const int tx = tid % 16;
    const int ty = tid / 16;
    const int row0 = blockIdx.y * BMF;
    const int col0 = blockIdx.x * BNF;
    float acc[4][4] = {};
    const int ra = tid / 4;
    const int ca = 4 * (tid % 4);
    const int rb = tid / 16;
    const int cb = 4 * (tid % 16);
    for (int k0 = 0; k0 < K; k0 += BKF) {
        float4 v = *(const float4*)(A0 + (size_t)(row0 + ra) * K + k0 + ca);
        float4 bvec = *(const float4*)(W + (size_t)(k0 + rb) * N + col0 + cb);
        As[ca + 0][ra] = v.x;
        As[ca + 1][ra] = v.y;
        As[ca + 2][ra] = v.z;
        As[ca + 3][ra] = v.w;
        *(float4*)&Bs[rb][cb] = bvec;
        __syncthreads();
#pragma unroll
        for (int kk = 0; kk < BKF; ++kk) {
            float4 av = *(const float4*)&As[kk][ty * 4];
            float4 bv = *(const float4*)&Bs[kk][tx * 4];
            float a_[4] = {av.x, av.y, av.z, av.w};
            float b_[4] = {bv.x, bv.y, bv.z, bv.w};
#pragma unroll
            for (int i = 0; i < 4; ++i)
#pragma unroll
                for (int j = 0; j < 4; ++j)
                    acc[i][j] = fmaf(a_[i], b_[j], acc[i][j]);
        }
        __syncthreads();
    }
    float4 bv = *(const float4*)(bias + col0 + tx * 4);
    float bb[4] = {bv.x, bv.y, bv.z, bv.w};
#pragma unroll
    for (int i = 0; i < 4; ++i) {
        float4 o;
        o.x = fmaxf(acc[i][0] + bb[0], 0.f);
        o.y = fmaxf(acc[i][1] + bb[1], 0.f);
        o.z = fmaxf(acc[i][2] + bb[2], 0.f);
        o.w = fmaxf(acc[i][3] + bb[3], 0.f);
        *(float4*)(C + (size_t)(row0 + ty * 4 + i) * N + col0 + tx * 4) = o;
    }
}

// ---------------- weight prep: transpose + split ----------------------------
__global__ __launch_bounds__(256) void prep_wt(
    const float* __restrict__ w, ushort_t* __restrict__ th,
    ushort_t* __restrict__ tl, int K, int N)
{
    int idx = blockIdx.x * 256 + threadIdx.x;   // n*K + k
    int n = idx / K, k = idx % K;
    float v = w[(size_t)k * N + n];
    split2(v, th[idx], tl[idx]);
}

// ---------------- init: io = inp + out_e ; xs = split(io + lat_e) -----------
__global__ __launch_bounds__(256) void init_xs(
    const float* __restrict__ inpf, const float* __restrict__ oute,
    const float* __restrict__ late, float* __restrict__ io,
    ushort_t* __restrict__ xh, ushort_t* __restrict__ xl)
{
    int i = blockIdx.x * 256 + threadIdx.x;     // 1024*512
    float t = inpf[i] + oute[i];
    io[i] = t;
    split2(t + late[i], xh[i], xl[i]);
}

// ---------------- barrier init ---------------------------------------------
__global__ void init_bar(unsigned* bar) {
    bar[threadIdx.x] = 0;
    bar[threadIdx.x + 256] = 0;
}

// ---------------------------------------------------------------------------
// Persistent TRM kernel. grid = 256 blocks (one per CU), 256 threads.
// Two-level grid barrier: 8 group counters (one 128B line each) + root.
// Monotonic epochs (no counter reset -> no reset race).
// ---------------------------------------------------------------------------
__device__ __forceinline__ void grid_barrier(unsigned* bar, unsigned& tgt)
{
    __syncthreads();
    if (threadIdx.x == 0) {
        unsigned g = blockIdx.x >> 5;          // 8 groups x 32 blocks
        __threadfence();                       // device-scope release of our stores
        unsigned old = __hip_atomic_fetch_add(bar + g * 32, 1u,
                                              __ATOMIC_ACQ_REL, __HIP_MEMORY_SCOPE_AGENT);
        if ((old & 31u) == 31u)
            __hip_atomic_fetch_add(bar + 256, 1u,
                                   __ATOMIC_ACQ_REL, __HIP_MEMORY_SCOPE_AGENT);
        while (__hip_atomic_load(bar + 256, __ATOMIC_ACQUIRE,
                                 __HIP_MEMORY_SCOPE_AGENT) < tgt)
            __builtin_amdgcn_s_sleep(1);
    }
    tgt += 8;
    __syncthreads();
}

// stage: global -> regs (prefetch), regs -> LDS (XOR-swizzled [m][c^(m&7)])
template <int BM, int BN, int K>
__device__ __forceinline__ void stage_load(
    const ushort_t* __restrict__ Ah, const ushort_t* __restrict__ Al,
    const ushort_t* __restrict__ Wh, const ushort_t* __restrict__ Wl,
    int row0, int col0, int k0e, int tid, uint4* pa, uint4* pb)
{
    constexpr int AIT = BM * 16 / 256;
    constexpr int BIT = BN * 16 / 256;
#pragma unroll
    for (int t = 0; t < AIT; ++t) {
        int i = tid + t * 256;
        int comp = i / (BM * 8);
        int rid = i % (BM * 8);
        int m = rid >> 3, c = rid & 7;
        const ushort_t* src = (comp ? Al : Ah) + (size_t)(row0 + m) * K + k0e + c * 8;
        pa[t] = *(const uint4*)src;
    }
#pragma unroll
    for (int t = 0; t < BIT; ++t) {
        int i = tid + t * 256;
        int comp = i / (BN * 8);
        int rid = i % (BN * 8);
        int n = rid >> 3, c = rid & 7;
        const ushort_t* src = (comp ? Wl : Wh) + (size_t)(col0 + n) * K + k0e + c * 8;
        pb[t] = *(const uint4*)src;
    }
}

template <int BM, int BN>
__device__ __forceinline__ void stage_store(
    unsigned char* buf, int tid, const uint4* pa, const uint4* pb)
{
    constexpr int AIT = BM * 16 / 256;
    constexpr int BIT = BN * 16 / 256;
#pragma unroll
    for (int t = 0; t < AIT; ++t) {
        int i = tid + t * 256;
        int comp = i / (BM * 8);
        int rid = i % (BM * 8);
        int m = rid >> 3, c = rid & 7;
        *(uint4*)(buf + comp * (BM * 128) + (((m << 3) | (c ^ (m & 7))) << 4)) = pa[t];
    }
#pragma unroll
    for (int t = 0; t < BIT; ++t) {
        int i = tid + t * 256;
        int comp = i / (BN * 8);
        int rid = i % (BN * 8);
        int n = rid >> 3, c = rid & 7;
        *(uint4*)(buf + BM * 256 + comp * (BN * 128) + (((n << 3) | (c ^ (n & 7))) << 4)) = pb[t];
    }
}

template <int BM, int BN>
__device__ __forceinline__ void compute_tile(
    const unsigned char* buf, int m_off, int n_off, int q, int li,
    f32x4 acc[BM / 32][BN / 32])
{
    constexpr int MI = BM / 32, NJ = BN / 32;
#pragma unroll
    for (int s = 0; s < 2; ++s) {
        const int cbase = s * 4 + q;
        short8 ah[MI], al[MI], bh[NJ], bl[NJ];
#pragma unroll
        for (int ti = 0; ti < MI; ++ti) {
            int m = m_off + ti * 16 + li;
            int sl = ((m << 3) | (cbase ^ (m & 7))) << 4;
            ah[ti] = *(const short8*)(buf + sl);
            al[ti] = *(const short8*)(buf + BM * 128 + sl);
        }
#pragma unroll
        for (int tj = 0; tj < NJ; ++tj) {
            int n = n_off + tj * 16 + li;
            int sl = ((n << 3) | (cbase ^ (n & 7))) << 4;
            bh[tj] = *(const short8*)(buf + BM * 256 + sl);
            bl[tj] = *(const short8*)(buf + BM * 256 + BN * 128 + sl);
        }
#pragma unroll
        for (int ti = 0; ti < MI; ++ti)
#pragma unroll
            for (int tj = 0; tj < NJ; ++tj) {
                acc[ti][tj] = __builtin_amdgcn_mfma_f32_16x16x32_bf16(ah[ti], bh[tj], acc[ti][tj], 0, 0, 0);
                acc[ti][tj] = __builtin_amdgcn_mfma_f32_16x16x32_bf16(ah[ti], bl[tj], acc[ti][tj], 0, 0, 0);
                acc[ti][tj] = __builtin_amdgcn_mfma_f32_16x16x32_bf16(al[ti], bh[tj], acc[ti][tj], 0, 0, 0);
                acc[ti][tj] = __builtin_amdgcn_mfma_f32_16x16x32_bf16(al[ti], bl[tj], acc[ti][tj], 0, 0, 0);
            }
    }
}

// epilogue modes (C layout: col = lane&15, row = quad*4 + reg):
//  0: split C -> oh/ol                                  (backbone GEMM1)
//  1: split(io + v)                                     (lat iters 0..4)
//  2: split(inpf + v); latf = v                         (lat iter 5)
//  3: outf = v; t=inpf+v; io=t; split(t + latf)         (out update)
template <int BM, int BN>
__device__ __forceinline__ void epilogue(
    f32x4 acc[BM / 32][BN / 32], int row0, int col0, int m_off, int n_off,
    int q, int li, const float* __restrict__ bias, int N, int mode,
    ushort_t* __restrict__ oh, ushort_t* __restrict__ ol,
    float* __restrict__ io, const float* __restrict__ inpf,
    float* __restrict__ latf, float* __restrict__ outf)
{
    constexpr int MI = BM / 32, NJ = BN / 32;
#pragma unroll
    for (int ti = 0; ti < MI; ++ti)
#pragma unroll
        for (int tj = 0; tj < NJ; ++tj) {
            int colg = col0 + n_off + tj * 16 + li;
            float bv = bias[colg];
#pragma unroll
            for (int rr = 0; rr < 4; ++rr) {
                int rowg = row0 + m_off + ti * 16 + q * 4 + rr;
                size_t idx = (size_t)rowg * N + colg;
                float v = fmaxf(acc[ti][tj][rr] + bv, 0.f);
                if (mode == 0) {
                    split2(v, oh[idx], ol[idx]);
                } else if (mode == 1) {
                    split2(io[idx] + v, oh[idx], ol[idx]);
                } else if (mode == 2) {
                    split2(inpf[idx] + v, oh[idx], ol[idx]);
                    latf[idx] = v;
                } else {
                    outf[idx] = v;
                    float t2 = inpf[idx] + v;
                    io[idx] = t2;
                    split2(t2 + latf[idx], oh[idx], ol[idx]);
                }
            }
        }
}

__global__ __launch_bounds__(256, 1) void trm_persist(
    ushort_t* __restrict__ xs_hi, ushort_t* __restrict__ xs_lo,
    ushort_t* __restrict__ h1_hi, ushort_t* __restrict__ h1_lo,
    const ushort_t* __restrict__ W1h, const ushort_t* __restrict__ W1l,
    const ushort_t* __restrict__ W2h, const ushort_t* __restrict__ W2l,
    const float* __restrict__ bb1, const float* __restrict__ bb2,
    float* __restrict__ io, const float* __restrict__ inpf,
    float* __restrict__ latf, float* __restrict__ outf,
    const float* __restrict__ hw, const float* __restrict__ hb,
    float* __restrict__ logits, unsigned* bar)
{
    __shared__ __align__(16) unsigned char lds[65536];   // 2 x 32KB buffers
    const int tid = threadIdx.x;
    const int w = tid >> 6, lane = tid & 63;
    const int q = lane >> 4, li = lane & 15;
    const int bid = blockIdx.x;
    unsigned tgt = 8;

    // tile coords
    const int r0_g1 = (bid >> 4) * 64, c0_g1 = (bid & 15) * 64;   // 16x16 tiles
    const int r0_g2 = (bid >> 3) * 32, c0_g2 = (bid & 7) * 64;    // 32x8 tiles
    const int mo_g1 = (w & 1) * 32, no_g1 = (w >> 1) * 32;
    const int mo_g2 = (w & 1) * 16, no_g2 = (w >> 1) * 32;

    for (int step = 0; step < 336; ++step) {              // 48 sup * 7
        // ---- GEMM1: h1 = relu(xs @ W1 + bb1)  [1024x1024, K=512] ----
        {
            f32x4 acc[2][2] = {};
            uint4 pa[4], pb[4];
            stage_load<64, 64, 512>(xs_hi, xs_lo, W1h, W1l, r0_g1, c0_g1, 0, tid, pa, pb);
            for (int r = 0; r < 8; ++r) {
                unsigned char* buf = lds + (r & 1) * 32768;
                stage_store<64, 64>(buf, tid, pa, pb);
                __syncthreads();
                if (r < 7)
                    stage_load<64, 64, 512>(xs_hi, xs_lo, W1h, W1l, r0_g1, c0_g1,
                                            (r + 1) * 64, tid, pa, pb);
                compute_tile<64, 64>(buf, mo_g1, no_g1, q, li, acc);
            }
            epilogue<64, 64>(acc, r0_g1, c0_g1, mo_g1, no_g1, q, li, bb1, 1024, 0,
                             h1_hi, h1_lo, io, inpf, latf, outf);
        }
        grid_barrier(bar, tgt);

        // ---- GEMM2: xs' = f(relu(h1 @ W2 + bb2))  [1024x512, K=1024] ----
        {
            int im = step % 7;
            int mode = (im < 5) ? 1 : ((im == 5) ? 2 : 3);
            f32x4 acc[1][2] = {};
            uint4 pa[2], pb[4];
            stage_load<32, 64, 1024>(h1_hi, h1_lo, W2h, W2l, r0_g2, c0_g2, 0, tid, pa, pb);
            for (int r = 0; r < 16; ++r) {
                unsigned char* buf = lds + (r & 1) * 32768;
                stage_store<32, 64>(buf, tid, pa, pb);
                __syncthreads();
                if (r < 15)
                    stage_load<32, 64, 1024>(h1_hi, h1_lo, W2h, W2l, r0_g2, c0_g2,
                                             (r + 1) * 64, tid, pa, pb);
                compute_tile<32, 64>(buf, mo_g2, no_g2, q, li, acc);
            }
            epilogue<32, 64>(acc, r0_g2, c0_g2, mo_g2, no_g2, q, li, bb2, 512, mode,
                             xs_hi, xs_lo, io, inpf, latf, outf);
        }
        grid_barrier(bar, tgt);
    }

    // ---- head: logits(1024,10) = out @ head_w + head_b ----
    if (bid < 40) {
        int idx = bid * 256 + tid;
        int j = idx % 10, b = idx / 10;
        const float* r = outf + (size_t)b * 512;
        float s = hb[j];
        for (int k = 0; k < 512; ++k) s = fmaf(r[k], hw[k * 10 + j], s);
        logits[idx] = s;
    }
}

extern "C" void kernel_launch(void* const* d_in, const int* in_sizes, int n_in,
                              void* d_out, int out_size, void* d_ws, size_t ws_size,
                              hipStream_t stream)
{
    const float* raw   = (const float*)d_in[0];
    const float* out_e = (const float*)d_in[1];
    const float* lat_e = (const float*)d_in[2];
    const float* c1w = (const float*)d_in[3];
    const float* c1b = (const float*)d_in[4];
    const float* c2w = (const float*)d_in[5];
    const float* c2b = (const float*)d_in[6];
    const float* pw1 = (const float*)d_in[7];
    const float* pb1 = (const float*)d_in[8];
    const float* pw2 = (const float*)d_in[9];
    const float* pb2 = (const float*)d_in[10];
    const float* bw1 = (const float*)d_in[11];
    const float* bb1 = (const float*)d_in[12];
    const float* bw2 = (const float*)d_in[13];
    const float* bb2 = (const float*)d_in[14];
    const float* hw  = (const float*)d_in[15];
    const float* hb  = (const float*)d_in[16];
    // d_in[17]=Nsup(16), d_in[18]=n_latent(6): fixed, hard-coded.

    char* base = (char*)d_ws;
    float*    pool1  = (float*)   (base + 0);          // conv1 out (pre-backbone)
    ushort_t* h1_hi  = (ushort_t*)(base + 0);
    ushort_t* h1_lo  = (ushort_t*)(base + 2097152);
    ushort_t* xs_hi  = (ushort_t*)(base + 4194304);
    ushort_t* xs_lo  = (ushort_t*)(base + 5242880);
    float*    io     = (float*)   (base + 6291456);
    float*    latf   = (float*)   (base + 8388608);
    float*    h1f    = (float*)   (base + 0);          // proj1 out (pre-backbone)
    float*    h      = (float*)   (base + 12845056);   // conv2 out fp32
    float*    inpf   = (float*)   (base + 19267584);
    float*    outf   = (float*)   (base + 21364736);
    ushort_t* bW1t_h = (ushort_t*)(base + 23461888);   // [1024n][512k]
    ushort_t* bW1t_l = (ushort_t*)(base + 24510464);
    ushort_t* bW2t_h = (ushort_t*)(base + 25559040);   // [512n][1024k]
    ushort_t* bW2t_l = (ushort_t*)(base + 26607616);
    unsigned* bar    = (unsigned*)(base + 27656192);   // 2KB barrier lines

    // weight prep (every launch; ws is re-poisoned by harness)
    prep_wt<<<2048, 256, 0, stream>>>(bw1, bW1t_h, bW1t_l, 512, 1024);
    prep_wt<<<2048, 256, 0, stream>>>(bw2, bW2t_h, bW2t_l, 1024, 512);
    init_bar<<<1, 256, 0, stream>>>(bar);

    // fp32 prologue
    conv1_pool<<<3211264 / 256, 256, 0, stream>>>(raw, c1w, c1b, pool1);
    conv2_pool<<<1605632 / 256, 256, 0, stream>>>(pool1, c2w, c2b, h);
    gemm_f32<<<dim3(16, 16), 256, 0, stream>>>(h, pw1, pb1, h1f, 1024, 1024, 1568);
    gemm_f32<<<dim3(8, 16), 256, 0, stream>>>(h1f, pw2, pb2, inpf, 1024, 512, 1024);
    init_xs<<<2048, 256, 0, stream>>>(inpf, out_e, lat_e, io, xs_hi, xs_lo);

    // the whole recursion + head in ONE persistent kernel
    trm_persist<<<256, 256, 0, stream>>>(
        xs_hi, xs_lo, h1_hi, h1_lo, bW1t_h, bW1t_l, bW2t_h, bW2t_l,
        bb1, bb2, io, inpf, latf, outf, hw, hb, (float*)d_out, bar);
}

// Round 4
// 18460.872 us; speedup vs baseline: 1.8914x; 1.8914x over previous
//
#include <hip/hip_runtime.h>
#include <hip/hip_bf16.h>

// ---------------------------------------------------------------------------
// SimpleCNN / TRM forward. Round 4: persistent kernel with XCD-local dataflow.
// Round-3 counters: MfmaUtil 3.5%, FETCH 9.2GB -> the agent-scope ACQUIRE spin
// emitted an L2 invalidate per poll, nuking the XCD L2 under co-resident
// compute blocks. Fix: (1) relaxed spin, one fence at entry/exit; (2) rows
// partitioned by bid&7 so producer->consumer edges stay inside one XCD ->
// barrier needs only L1 inv (buffer_inv sc0), L2 stays warm; per-group (32
// block) barriers replace the grid barrier. Physical mapping VERIFIED at
// runtime via s_getreg(HW_REG_XCC_ID); if a bid-group spans 2 XCDs we fall
// back to agent-scope fences (correct under any mapping).
// Math identical to rounds 2/3: split-bf16 MFMA, fp32 prologue.
// ---------------------------------------------------------------------------

typedef unsigned short ushort_t;
typedef __attribute__((ext_vector_type(8))) short short8;
typedef __attribute__((ext_vector_type(4))) float f32x4;

__device__ inline unsigned f2bf_rne(float v) {
    unsigned u = __float_as_uint(v);
    return (u + 0x7fffu + ((u >> 16) & 1u)) >> 16;
}
__device__ inline void split2(float v, ushort_t& h, ushort_t& l) {
    unsigned uh = f2bf_rne(v);
    h = (ushort_t)uh;
    float fh = __uint_as_float(uh << 16);
    l = (ushort_t)f2bf_rne(v - fh);
}

// ---------------- conv1 (1->16, 3x3 SAME, 28x28) + relu + maxpool2 ----------
__global__ __launch_bounds__(256) void conv1_pool(
    const float* __restrict__ in, const float* __restrict__ w,
    const float* __restrict__ bias, float* __restrict__ out)
{
    int idx = blockIdx.x * 256 + threadIdx.x;   // 1024*16*14*14
    int xo = idx % 14; int t = idx / 14;
    int yo = t % 14;  t /= 14;
    int oc = t % 16;  int b = t / 16;
    const float* ip = in + (size_t)b * 784;
    const float* wp = w + oc * 9;
    float win[4][4];
#pragma unroll
    for (int yy = 0; yy < 4; ++yy)
#pragma unroll
        for (int xx = 0; xx < 4; ++xx) {
            int y = 2 * yo + yy - 1, x = 2 * xo + xx - 1;
            win[yy][xx] = (y >= 0 && y < 28 && x >= 0 && x < 28) ? ip[y * 28 + x] : 0.f;
        }
    float bs = bias[oc];
    float m = -1e30f;
#pragma unroll
    for (int py = 0; py < 2; ++py)
#pragma unroll
        for (int px = 0; px < 2; ++px) {
            float s = bs;
#pragma unroll
            for (int dy = 0; dy < 3; ++dy)
#pragma unroll
                for (int dx = 0; dx < 3; ++dx)
                    s = fmaf(win[py + dy][px + dx], wp[dy * 3 + dx], s);
            m = fmaxf(m, s);
        }
    out[idx] = fmaxf(m, 0.f);
}

// ---------------- conv2 (16->32, 3x3 SAME, 14x14) + relu + maxpool2 ---------
__global__ __launch_bounds__(256) void conv2_pool(
    const float* __restrict__ in, const float* __restrict__ w,
    const float* __restrict__ bias, float* __restrict__ out)
{
    __shared__ float ws_[32 * 16 * 9];
    for (int i = threadIdx.x; i < 4608; i += 256) ws_[i] = w[i];
    __syncthreads();
    int idx = blockIdx.x * 256 + threadIdx.x;   // 1024*32*7*7
    int xo = idx % 7; int t = idx / 7;
    int yo = t % 7;  t /= 7;
    int oc = t % 32; int b = t / 32;
    const float* ip = in + (size_t)b * 16 * 196;
    float bs = bias[oc];
    float s00 = bs, s01 = bs, s10 = bs, s11 = bs;
    for (int ic = 0; ic < 16; ++ic) {
        const float* ipp = ip + ic * 196;
        float win[4][4];
#pragma unroll
        for (int yy = 0; yy < 4; ++yy)
#pragma unroll
            for (int xx = 0; xx < 4; ++xx) {
                int y = 2 * yo + yy - 1, x = 2 * xo + xx - 1;
                win[yy][xx] = (y >= 0 && y < 14 && x >= 0 && x < 14) ? ipp[y * 14 + x] : 0.f;
            }
        const float* wp = ws_ + (oc * 16 + ic) * 9;
#pragma unroll
        for (int dy = 0; dy < 3; ++dy)
#pragma unroll
            for (int dx = 0; dx < 3; ++dx) {
                float wv = wp[dy * 3 + dx];
                s00 = fmaf(win[0 + dy][0 + dx], wv, s00);
                s01 = fmaf(win[0 + dy][1 + dx], wv, s01);
                s10 = fmaf(win[1 + dy][0 + dx], wv, s10);
                s11 = fmaf(win[1 + dy][1 + dx], wv, s11);
            }
    }
    float m = fmaxf(fmaxf(s00, s01), fmaxf(s10, s11));
    out[idx] = fmaxf(m, 0.f);
}

// ---------------- fp32 tiled GEMM (prologue only: proj1, proj2) -------------
#define BMF 64
#define BNF 64
#define BKF 16

__global__ __launch_bounds__(256) void gemm_f32(
    const float* __restrict__ A0, const float* __restrict__ W,
    const float* __restrict__ bias, float* __restrict__ C,
    int M, int N, int K)
{
    __shared__ float As[BKF][BMF];
    __shared__ float Bs[BKF][BNF];
    const int tid = threadIdx.x;
    const int tx = tid % 16;
    const int ty = tid / 16;
    const int row0 = blockIdx.y * BMF;
    const int col0 = blockIdx.x * BNF;
    float acc[4][4] = {};
    const int ra = tid / 4;
    const int ca = 4 * (tid % 4);
    const int rb = tid / 16;
    const int cb = 4 * (tid % 16);
    for (int k0 = 0; k0 < K; k0 += BKF) {
        float4 v = *(const float4*)(A0 + (size_t)(row0 + ra) * K + k0 + ca);
        float4 bvec = *(const float4*)(W + (size_t)(k0 + rb) * N + col0 + cb);
        As[ca + 0][ra] = v.x;
        As[ca + 1][ra] = v.y;
        As[ca + 2][ra] = v.z;
        As[ca + 3][ra] = v.w;
        *(float4*)&Bs[rb][cb] = bvec;
        __syncthreads();
#pragma unroll
        for (int kk = 0; kk < BKF; ++kk) {
            float4 av = *(const float4*)&As[kk][ty * 4];
            float4 bv = *(const float4*)&Bs[kk][tx * 4];
            float a_[4] = {av.x, av.y, av.z, av.w};
            float b_[4] = {bv.x, bv.y, bv.z, bv.w};
#pragma unroll
            for (int i = 0; i < 4; ++i)
#pragma unroll
                for (int j = 0; j < 4; ++j)
                    acc[i][j] = fmaf(a_[i], b_[j], acc[i][j]);
        }
        __syncthreads();
    }
    float4 bv = *(const float4*)(bias + col0 + tx * 4);
    float bb[4] = {bv.x, bv.y, bv.z, bv.w};
#pragma unroll
    for (int i = 0; i < 4; ++i) {
        float4 o;
        o.x = fmaxf(acc[i][0] + bb[0], 0.f);
        o.y = fmaxf(acc[i][1] + bb[1], 0.f);
        o.z = fmaxf(acc[i][2] + bb[2], 0.f);
        o.w = fmaxf(acc[i][3] + bb[3], 0.f);
        *(float4*)(C + (size_t)(row0 + ty * 4 + i) * N + col0 + tx * 4) = o;
    }
}

// ---------------- weight prep: transpose + split ----------------------------
__global__ __launch_bounds__(256) void prep_wt(
    const float* __restrict__ w, ushort_t* __restrict__ th,
    ushort_t* __restrict__ tl, int K, int N)
{
    int idx = blockIdx.x * 256 + threadIdx.x;   // n*K + k
    int n = idx / K, k = idx % K;
    float v = w[(size_t)k * N + n];
    split2(v, th[idx], tl[idx]);
}

// ---------------- init: io = inp + out_e ; xs = split(io + lat_e) -----------
__global__ __launch_bounds__(256) void init_xs(
    const float* __restrict__ inpf, const float* __restrict__ oute,
    const float* __restrict__ late, float* __restrict__ io,
    ushort_t* __restrict__ xh, ushort_t* __restrict__ xl)
{
    int i = blockIdx.x * 256 + threadIdx.x;     // 1024*512
    float t = inpf[i] + oute[i];
    io[i] = t;
    split2(t + late[i], xh[i], xl[i]);
}

// ---------------- barrier init ---------------------------------------------
__global__ void init_bar(unsigned* bar) {
    bar[threadIdx.x] = 0;          // [0..255]: group counters (g*32)
    bar[threadIdx.x + 256] = 0;    // [256..511]: [320..327] = group XCD masks
}

// ---------------------------------------------------------------------------
// Per-group (32-block) barrier. Relaxed spin (NO per-poll cache invalidate).
// fast: producer/consumer verified same-XCD -> release = waitcnt only,
//       acquire = L1-only invalidate (buffer_inv sc0); L2 stays warm.
// safe: agent-scope fences (L2 wb/inv) -- correct under any block->XCD map.
// ---------------------------------------------------------------------------
__device__ __forceinline__ void group_barrier(unsigned* bar, int g,
                                              unsigned& tgt, int fast)
{
    __syncthreads();
    if (threadIdx.x == 0) {
        if (fast) __builtin_amdgcn_fence(__ATOMIC_RELEASE, "workgroup");
        else      __builtin_amdgcn_fence(__ATOMIC_RELEASE, "agent");
        __hip_atomic_fetch_add(bar + g * 32, 1u, __ATOMIC_RELAXED,
                               __HIP_MEMORY_SCOPE_AGENT);
        while (__hip_atomic_load(bar + g * 32, __ATOMIC_RELAXED,
                                 __HIP_MEMORY_SCOPE_AGENT) < tgt)
            __builtin_amdgcn_s_sleep(1);
        if (fast) {
            __builtin_amdgcn_fence(__ATOMIC_ACQUIRE, "workgroup");
            asm volatile("buffer_inv sc0" ::: "memory");   // vector L1 inv only
        } else {
            __builtin_amdgcn_fence(__ATOMIC_ACQUIRE, "agent");
        }
    }
    tgt += 32;
    __syncthreads();
}

// stage: global -> regs (prefetch), regs -> LDS (XOR-swizzled [m][c^(m&7)])
template <int BM, int BN, int K>
__device__ __forceinline__ void stage_load(
    const ushort_t* __restrict__ Ah, const ushort_t* __restrict__ Al,
    const ushort_t* __restrict__ Wh, const ushort_t* __restrict__ Wl,
    int row0, int col0, int k0e, int tid, uint4* pa, uint4* pb)
{
    constexpr int AIT = BM * 16 / 256;
    constexpr int BIT = BN * 16 / 256;
#pragma unroll
    for (int t = 0; t < AIT; ++t) {
        int i = tid + t * 256;
        int comp = i / (BM * 8);
        int rid = i % (BM * 8);
        int m = rid >> 3, c = rid & 7;
        const ushort_t* src = (comp ? Al : Ah) + (size_t)(row0 + m) * K + k0e + c * 8;
        pa[t] = *(const uint4*)src;
    }
#pragma unroll
    for (int t = 0; t < BIT; ++t) {
        int i = tid + t * 256;
        int comp = i / (BN * 8);
        int rid = i % (BN * 8);
        int n = rid >> 3, c = rid & 7;
        const ushort_t* src = (comp ? Wl : Wh) + (size_t)(col0 + n) * K + k0e + c * 8;
        pb[t] = *(const uint4*)src;
    }
}

template <int BM, int BN>
__device__ __forceinline__ void stage_store(
    unsigned char* buf, int tid, const uint4* pa, const uint4* pb)
{
    constexpr int AIT = BM * 16 / 256;
    constexpr int BIT = BN * 16 / 256;
#pragma unroll
    for (int t = 0; t < AIT; ++t) {
        int i = tid + t * 256;
        int comp = i / (BM * 8);
        int rid = i % (BM * 8);
        int m = rid >> 3, c = rid & 7;
        *(uint4*)(buf + comp * (BM * 128) + (((m << 3) | (c ^ (m & 7))) << 4)) = pa[t];
    }
#pragma unroll
    for (int t = 0; t < BIT; ++t) {
        int i = tid + t * 256;
        int comp = i / (BN * 8);
        int rid = i % (BN * 8);
        int n = rid >> 3, c = rid & 7;
        *(uint4*)(buf + BM * 256 + comp * (BN * 128) + (((n << 3) | (c ^ (n & 7))) << 4)) = pb[t];
    }
}

template <int BM, int BN>
__device__ __forceinline__ void compute_tile(
    const unsigned char* buf, int m_off, int n_off, int q, int li,
    f32x4 acc[BM / 32][BN / 32])
{
    constexpr int MI = BM / 32, NJ = BN / 32;
#pragma unroll
    for (int s = 0; s < 2; ++s) {
        const int cbase = s * 4 + q;
        short8 ah[MI], al[MI], bh[NJ], bl[NJ];
#pragma unroll
        for (int ti = 0; ti < MI; ++ti) {
            int m = m_off + ti * 16 + li;
            int sl = ((m << 3) | (cbase ^ (m & 7))) << 4;
            ah[ti] = *(const short8*)(buf + sl);
            al[ti] = *(const short8*)(buf + BM * 128 + sl);
        }
#pragma unroll
        for (int tj = 0; tj < NJ; ++tj) {
            int n = n_off + tj * 16 + li;
            int sl = ((n << 3) | (cbase ^ (n & 7))) << 4;
            bh[tj] = *(const short8*)(buf + BM * 256 + sl);
            bl[tj] = *(const short8*)(buf + BM * 256 + BN * 128 + sl);
        }
#pragma unroll
        for (int ti = 0; ti < MI; ++ti)
#pragma unroll
            for (int tj = 0; tj < NJ; ++tj) {
                acc[ti][tj] = __builtin_amdgcn_mfma_f32_16x16x32_bf16(ah[ti], bh[tj], acc[ti][tj], 0, 0, 0);
                acc[ti][tj] = __builtin_amdgcn_mfma_f32_16x16x32_bf16(ah[ti], bl[tj], acc[ti][tj], 0, 0, 0);
                acc[ti][tj] = __builtin_amdgcn_mfma_f32_16x16x32_bf16(al[ti], bh[tj], acc[ti][tj], 0, 0, 0);
                acc[ti][tj] = __builtin_amdgcn_mfma_f32_16x16x32_bf16(al[ti], bl[tj], acc[ti][tj], 0, 0, 0);
            }
    }
}

// epilogue modes (C layout: col = lane&15, row = quad*4 + reg):
//  0: split C -> oh/ol                                  (backbone GEMM1)
//  1: split(io + v)                                     (lat iters 0..4)
//  2: split(inpf + v); latf = v                         (lat iter 5)
//  3: outf = v; t=inpf+v; io=t; split(t + latf)         (out update)
template <int BM, int BN>
__device__ __forceinline__ void epilogue(
    f32x4 acc[BM / 32][BN / 32], int row0, int col0, int m_off, int n_off,
    int q, int li, const float* __restrict__ bias, int N, int mode,
    ushort_t* __restrict__ oh, ushort_t* __restrict__ ol,
    float* __restrict__ io, const float* __restrict__ inpf,
    float* __restrict__ latf, float* __restrict__ outf)
{
    constexpr int MI = BM / 32, NJ = BN / 32;
#pragma unroll
    for (int ti = 0; ti < MI; ++ti)
#pragma unroll
        for (int tj = 0; tj < NJ; ++tj) {
            int colg = col0 + n_off + tj * 16 + li;
            float bv = bias[colg];
#pragma unroll
            for (int rr = 0; rr < 4; ++rr) {
                int rowg = row0 + m_off + ti * 16 + q * 4 + rr;
                size_t idx = (size_t)rowg * N + colg;
                float v = fmaxf(acc[ti][tj][rr] + bv, 0.f);
                if (mode == 0) {
                    split2(v, oh[idx], ol[idx]);
                } else if (mode == 1) {
                    split2(io[idx] + v, oh[idx], ol[idx]);
                } else if (mode == 2) {
                    split2(inpf[idx] + v, oh[idx], ol[idx]);
                    latf[idx] = v;
                } else {
                    outf[idx] = v;
                    float t2 = inpf[idx] + v;
                    io[idx] = t2;
                    split2(t2 + latf[idx], oh[idx], ol[idx]);
                }
            }
        }
}

// ---------------------------------------------------------------------------
// Persistent TRM kernel. grid = 256 blocks. Group g = bid&7 owns rows
// [g*128, g*128+128) of ALL state (xs, h1, io, latf, outf) -> every
// producer->consumer edge is group-internal; with the verified bid->XCD
// round-robin mapping the whole recursion is XCD-local.
// ---------------------------------------------------------------------------
__global__ __launch_bounds__(256, 1) void trm_persist(
    ushort_t* __restrict__ xs_hi, ushort_t* __restrict__ xs_lo,
    ushort_t* __restrict__ h1_hi, ushort_t* __restrict__ h1_lo,
    const ushort_t* __restrict__ W1h, const ushort_t* __restrict__ W1l,
    const ushort_t* __restrict__ W2h, const ushort_t* __restrict__ W2l,
    const float* __restrict__ bb1, const float* __restrict__ bb2,
    float* __restrict__ io, const float* __restrict__ inpf,
    float* __restrict__ latf, float* __restrict__ outf,
    const float* __restrict__ hw, const float* __restrict__ hb,
    float* __restrict__ logits, unsigned* bar)
{
    __shared__ __align__(16) unsigned char lds[65536];   // 2 x 32KB buffers
    const int tid = threadIdx.x;
    const int w = tid >> 6, lane = tid & 63;
    const int q = lane >> 4, li = lane & 15;
    const int bid = blockIdx.x;
    const int g = bid & 7;            // row group (intended XCD)
    const int slot = bid >> 3;        // 0..31 within group

    // --- mode probe: is this bid-group entirely on one physical XCD? ---
    if (tid == 0) {
        unsigned xcc;
        asm volatile("s_getreg_b32 %0, hwreg(HW_REG_XCC_ID)" : "=s"(xcc));
        __hip_atomic_fetch_or(bar + 320 + g, 1u << (xcc & 31u),
                              __ATOMIC_RELAXED, __HIP_MEMORY_SCOPE_AGENT);
        __hip_atomic_fetch_add(bar + g * 32, 1u, __ATOMIC_RELAXED,
                               __HIP_MEMORY_SCOPE_AGENT);
        while (__hip_atomic_load(bar + g * 32, __ATOMIC_RELAXED,
                                 __HIP_MEMORY_SCOPE_AGENT) < 32u)
            __builtin_amdgcn_s_sleep(1);
        __builtin_amdgcn_fence(__ATOMIC_ACQUIRE, "agent");
        unsigned msk = __hip_atomic_load(bar + 320 + g, __ATOMIC_RELAXED,
                                         __HIP_MEMORY_SCOPE_AGENT);
        ((int*)lds)[0] = (__popc(msk) == 1) ? 1 : 0;
    }
    __syncthreads();
    const int fast = ((int*)lds)[0];
    __syncthreads();                  // everyone read mode before LDS reuse
    unsigned tgt = 64;                // initial barrier consumed 32

    // tile coords: rows local to group g for BOTH gemms
    const int r0_g1 = g * 128 + (slot >> 4) * 64;   // 2 x 64-row stripes
    const int c0_g1 = (slot & 15) * 64;             // 16 col tiles (N=1024)
    const int r0_g2 = g * 128 + (slot >> 3) * 32;   // 4 x 32-row stripes
    const int c0_g2 = (slot & 7) * 64;              // 8 col tiles (N=512)
    const int mo_g1 = (w & 1) * 32, no_g1 = (w >> 1) * 32;
    const int mo_g2 = (w & 1) * 16, no_g2 = (w >> 1) * 32;

    for (int step = 0; step < 336; ++step) {        // 48 sup * 7
        // ---- GEMM1: h1 = relu(xs @ W1 + bb1)  [rows g*128.., K=512] ----
        {
            f32x4 acc[2][2] = {};
            uint4 pa[4], pb[4];
            stage_load<64, 64, 512>(xs_hi, xs_lo, W1h, W1l, r0_g1, c0_g1, 0, tid, pa, pb);
            for (int r = 0; r < 8; ++r) {
                unsigned char* buf = lds + (r & 1) * 32768;
                stage_store<64, 64>(buf, tid, pa, pb);
                __syncthreads();
                if (r < 7)
                    stage_load<64, 64, 512>(xs_hi, xs_lo, W1h, W1l, r0_g1, c0_g1,
                                            (r + 1) * 64, tid, pa, pb);
                compute_tile<64, 64>(buf, mo_g1, no_g1, q, li, acc);
            }
            epilogue<64, 64>(acc, r0_g1, c0_g1, mo_g1, no_g1, q, li, bb1, 1024, 0,
                             h1_hi, h1_lo, io, inpf, latf, outf);
        }
        group_barrier(bar, g, tgt, fast);

        // ---- GEMM2: xs' = f(relu(h1 @ W2 + bb2))  [rows g*128.., K=1024] ----
        {
            int im = step % 7;
            int mode = (im < 5) ? 1 : ((im == 5) ? 2 : 3);
            f32x4 acc[1][2] = {};
            uint4 pa[2], pb[4];
            stage_load<32, 64, 1024>(h1_hi, h1_lo, W2h, W2l, r0_g2, c0_g2, 0, tid, pa, pb);
            for (int r = 0; r < 16; ++r) {
                unsigned char* buf = lds + (r & 1) * 32768;
                stage_store<32, 64>(buf, tid, pa, pb);
                __syncthreads();
                if (r < 15)
                    stage_load<32, 64, 1024>(h1_hi, h1_lo, W2h, W2l, r0_g2, c0_g2,
                                             (r + 1) * 64, tid, pa, pb);
                compute_tile<32, 64>(buf, mo_g2, no_g2, q, li, acc);
            }
            epilogue<32, 64>(acc, r0_g2, c0_g2, mo_g2, no_g2, q, li, bb2, 512, mode,
                             xs_hi, xs_lo, io, inpf, latf, outf);
        }
        group_barrier(bar, g, tgt, fast);
    }

    // ---- head: logits rows [g*128, g*128+128) -------------------------------
    if (slot < 5) {
        int idx = slot * 256 + tid;                 // 0..1279 within group
        if (idx < 1280) {
            int rloc = idx / 10, j = idx % 10;
            int row = g * 128 + rloc;
            const float* r = outf + (size_t)row * 512;
            float s = hb[j];
            for (int k = 0; k < 512; ++k) s = fmaf(r[k], hw[k * 10 + j], s);
            logits[row * 10 + j] = s;
        }
    }
}

extern "C" void kernel_launch(void* const* d_in, const int* in_sizes, int n_in,
                              void* d_out, int out_size, void* d_ws, size_t ws_size,
                              hipStream_t stream)
{
    const float* raw   = (const float*)d_in[0];
    const float* out_e = (const float*)d_in[1];
    const float* lat_e = (const float*)d_in[2];
    const float* c1w = (const float*)d_in[3];
    const float* c1b = (const float*)d_in[4];
    const float* c2w = (const float*)d_in[5];
    const float* c2b = (const float*)d_in[6];
    const float* pw1 = (const float*)d_in[7];
    const float* pb1 = (const float*)d_in[8];
    const float* pw2 = (const float*)d_in[9];
    const float* pb2 = (const float*)d_in[10];
    const float* bw1 = (const float*)d_in[11];
    const float* bb1 = (const float*)d_in[12];
    const float* bw2 = (const float*)d_in[13];
    const float* bb2 = (const float*)d_in[14];
    const float* hw  = (const float*)d_in[15];
    const float* hb  = (const float*)d_in[16];
    // d_in[17]=Nsup(16), d_in[18]=n_latent(6): fixed, hard-coded.

    char* base = (char*)d_ws;
    float*    pool1  = (float*)   (base + 0);          // conv1 out (pre-backbone)
    ushort_t* h1_hi  = (ushort_t*)(base + 0);
    ushort_t* h1_lo  = (ushort_t*)(base + 2097152);
    ushort_t* xs_hi  = (ushort_t*)(base + 4194304);
    ushort_t* xs_lo  = (ushort_t*)(base + 5242880);
    float*    io     = (float*)   (base + 6291456);
    float*    latf   = (float*)   (base + 8388608);
    float*    h1f    = (float*)   (base + 0);          // proj1 out (pre-backbone)
    float*    h      = (float*)   (base + 12845056);   // conv2 out fp32
    float*    inpf   = (float*)   (base + 19267584);
    float*    outf   = (float*)   (base + 21364736);
    ushort_t* bW1t_h = (ushort_t*)(base + 23461888);   // [1024n][512k]
    ushort_t* bW1t_l = (ushort_t*)(base + 24510464);
    ushort_t* bW2t_h = (ushort_t*)(base + 25559040);   // [512n][1024k]
    ushort_t* bW2t_l = (ushort_t*)(base + 26607616);
    unsigned* bar    = (unsigned*)(base + 27656192);   // 2KB barrier lines

    // weight prep (every launch; ws is re-poisoned by harness)
    prep_wt<<<2048, 256, 0, stream>>>(bw1, bW1t_h, bW1t_l, 512, 1024);
    prep_wt<<<2048, 256, 0, stream>>>(bw2, bW2t_h, bW2t_l, 1024, 512);
    init_bar<<<1, 256, 0, stream>>>(bar);

    // fp32 prologue
    conv1_pool<<<3211264 / 256, 256, 0, stream>>>(raw, c1w, c1b, pool1);
    conv2_pool<<<1605632 / 256, 256, 0, stream>>>(pool1, c2w, c2b, h);
    gemm_f32<<<dim3(16, 16), 256, 0, stream>>>(h, pw1, pb1, h1f, 1024, 1024, 1568);
    gemm_f32<<<dim3(8, 16), 256, 0, stream>>>(h1f, pw2, pb2, inpf, 1024, 512, 1024);
    init_xs<<<2048, 256, 0, stream>>>(inpf, out_e, lat_e, io, xs_hi, xs_lo);

    // the whole recursion + head in ONE persistent kernel
    trm_persist<<<256, 256, 0, stream>>>(
        xs_hi, xs_lo, h1_hi, h1_lo, bW1t_h, bW1t_l, bW2t_h, bW2t_l,
        bb1, bb2, io, inpf, latf, outf, hw, hb, (float*)d_out, bar);
}

// Round 5
// 9550.809 us; speedup vs baseline: 3.6559x; 1.9329x over previous
//
#include <hip/hip_runtime.h>
#include <hip/hip_bf16.h>

// ---------------------------------------------------------------------------
// SimpleCNN / TRM forward. Round 5: LDS-resident weights.
// Round-4 counters: FETCH 19MB/step (weights thrash the 4MB XCD L2 every
// step) + bimodal fence mode. Fix: each block owns fixed column slices
// (GEMM1: 32 cols, GEMM2: 16 cols) whose split-bf16 weights live PERMANENTLY
// in 128KB static LDS (gfx950: 160KB/CU). A-operands (group-row-local
// activations) are read as MFMA fragments straight from L2 with a depth-2
// register pipeline — no LDS staging, no per-step weight traffic.
// 128KB LDS also forces 1 block/CU. Math identical to rounds 2-4.
// ---------------------------------------------------------------------------

typedef unsigned short ushort_t;
typedef __attribute__((ext_vector_type(8))) short short8;
typedef __attribute__((ext_vector_type(4))) float f32x4;

__device__ inline unsigned f2bf_rne(float v) {
    unsigned u = __float_as_uint(v);
    return (u + 0x7fffu + ((u >> 16) & 1u)) >> 16;
}
__device__ inline void split2(float v, ushort_t& h, ushort_t& l) {
    unsigned uh = f2bf_rne(v);
    h = (ushort_t)uh;
    float fh = __uint_as_float(uh << 16);
    l = (ushort_t)f2bf_rne(v - fh);
}

// ---------------- conv1 (1->16, 3x3 SAME, 28x28) + relu + maxpool2 ----------
__global__ __launch_bounds__(256) void conv1_pool(
    const float* __restrict__ in, const float* __restrict__ w,
    const float* __restrict__ bias, float* __restrict__ out)
{
    int idx = blockIdx.x * 256 + threadIdx.x;   // 1024*16*14*14
    int xo = idx % 14; int t = idx / 14;
    int yo = t % 14;  t /= 14;
    int oc = t % 16;  int b = t / 16;
    const float* ip = in + (size_t)b * 784;
    const float* wp = w + oc * 9;
    float win[4][4];
#pragma unroll
    for (int yy = 0; yy < 4; ++yy)
#pragma unroll
        for (int xx = 0; xx < 4; ++xx) {
            int y = 2 * yo + yy - 1, x = 2 * xo + xx - 1;
            win[yy][xx] = (y >= 0 && y < 28 && x >= 0 && x < 28) ? ip[y * 28 + x] : 0.f;
        }
    float bs = bias[oc];
    float m = -1e30f;
#pragma unroll
    for (int py = 0; py < 2; ++py)
#pragma unroll
        for (int px = 0; px < 2; ++px) {
            float s = bs;
#pragma unroll
            for (int dy = 0; dy < 3; ++dy)
#pragma unroll
                for (int dx = 0; dx < 3; ++dx)
                    s = fmaf(win[py + dy][px + dx], wp[dy * 3 + dx], s);
            m = fmaxf(m, s);
        }
    out[idx] = fmaxf(m, 0.f);
}

// ---------------- conv2 (16->32, 3x3 SAME, 14x14) + relu + maxpool2 ---------
__global__ __launch_bounds__(256) void conv2_pool(
    const float* __restrict__ in, const float* __restrict__ w,
    const float* __restrict__ bias, float* __restrict__ out)
{
    __shared__ float ws_[32 * 16 * 9];
    for (int i = threadIdx.x; i < 4608; i += 256) ws_[i] = w[i];
    __syncthreads();
    int idx = blockIdx.x * 256 + threadIdx.x;   // 1024*32*7*7
    int xo = idx % 7; int t = idx / 7;
    int yo = t % 7;  t /= 7;
    int oc = t % 32; int b = t / 32;
    const float* ip = in + (size_t)b * 16 * 196;
    float bs = bias[oc];
    float s00 = bs, s01 = bs, s10 = bs, s11 = bs;
    for (int ic = 0; ic < 16; ++ic) {
        const float* ipp = ip + ic * 196;
        float win[4][4];
#pragma unroll
        for (int yy = 0; yy < 4; ++yy)
#pragma unroll
            for (int xx = 0; xx < 4; ++xx) {
                int y = 2 * yo + yy - 1, x = 2 * xo + xx - 1;
                win[yy][xx] = (y >= 0 && y < 14 && x >= 0 && x < 14) ? ipp[y * 14 + x] : 0.f;
            }
        const float* wp = ws_ + (oc * 16 + ic) * 9;
#pragma unroll
        for (int dy = 0; dy < 3; ++dy)
#pragma unroll
            for (int dx = 0; dx < 3; ++dx) {
                float wv = wp[dy * 3 + dx];
                s00 = fmaf(win[0 + dy][0 + dx], wv, s00);
                s01 = fmaf(win[0 + dy][1 + dx], wv, s01);
                s10 = fmaf(win[1 + dy][0 + dx], wv, s10);
                s11 = fmaf(win[1 + dy][1 + dx], wv, s11);
            }
    }
    float m = fmaxf(fmaxf(s00, s01), fmaxf(s10, s11));
    out[idx] = fmaxf(m, 0.f);
}

// ---------------- fp32 tiled GEMM (prologue only: proj1, proj2) -------------
#define BMF 64
#define BNF 64
#define BKF 16

__global__ __launch_bounds__(256) void gemm_f32(
    const float* __restrict__ A0, const float* __restrict__ W,
    const float* __restrict__ bias, float* __restrict__ C,
    int M, int N, int K)
{
    __shared__ float As[BKF][BMF];
    __shared__ float Bs[BKF][BNF];
    const int tid = threadIdx.x;
    const int tx = tid % 16;
    const int ty = tid / 16;
    const int row0 = blockIdx.y * BMF;
    const int col0 = blockIdx.x * BNF;
    float acc[4][4] = {};
    const int ra = tid / 4;
    const int ca = 4 * (tid % 4);
    const int rb = tid / 16;
    const int cb = 4 * (tid % 16);
    for (int k0 = 0; k0 < K; k0 += BKF) {
        float4 v = *(const float4*)(A0 + (size_t)(row0 + ra) * K + k0 + ca);
        float4 bvec = *(const float4*)(W + (size_t)(k0 + rb) * N + col0 + cb);
        As[ca + 0][ra] = v.x;
        As[ca + 1][ra] = v.y;
        As[ca + 2][ra] = v.z;
        As[ca + 3][ra] = v.w;
        *(float4*)&Bs[rb][cb] = bvec;
        __syncthreads();
#pragma unroll
        for (int kk = 0; kk < BKF; ++kk) {
            float4 av = *(const float4*)&As[kk][ty * 4];
            float4 bv = *(const float4*)&Bs[kk][tx * 4];
            float a_[4] = {av.x, av.y, av.z, av.w};
            float b_[4] = {bv.x, bv.y, bv.z, bv.w};
#pragma unroll
            for (int i = 0; i < 4; ++i)
#pragma unroll
                for (int j = 0; j < 4; ++j)
                    acc[i][j] = fmaf(a_[i], b_[j], acc[i][j]);
        }
        __syncthreads();
    }
    float4 bv = *(const float4*)(bias + col0 + tx * 4);
    float bb[4] = {bv.x, bv.y, bv.z, bv.w};
#pragma unroll
    for (int i = 0; i < 4; ++i) {
        float4 o;
        o.x = fmaxf(acc[i][0] + bb[0], 0.f);
        o.y = fmaxf(acc[i][1] + bb[1], 0.f);
        o.z = fmaxf(acc[i][2] + bb[2], 0.f);
        o.w = fmaxf(acc[i][3] + bb[3], 0.f);
        *(float4*)(C + (size_t)(row0 + ty * 4 + i) * N + col0 + tx * 4) = o;
    }
}

// ---------------- weight prep: transpose + split ----------------------------
__global__ __launch_bounds__(256) void prep_wt(
    const float* __restrict__ w, ushort_t* __restrict__ th,
    ushort_t* __restrict__ tl, int K, int N)
{
    int idx = blockIdx.x * 256 + threadIdx.x;   // n*K + k
    int n = idx / K, k = idx % K;
    float v = w[(size_t)k * N + n];
    split2(v, th[idx], tl[idx]);
}

// ---------------- init: io = inp + out_e ; xs = split(io + lat_e) -----------
__global__ __launch_bounds__(256) void init_xs(
    const float* __restrict__ inpf, const float* __restrict__ oute,
    const float* __restrict__ late, float* __restrict__ io,
    ushort_t* __restrict__ xh, ushort_t* __restrict__ xl)
{
    int i = blockIdx.x * 256 + threadIdx.x;     // 1024*512
    float t = inpf[i] + oute[i];
    io[i] = t;
    split2(t + late[i], xh[i], xl[i]);
}

// ---------------- barrier init ---------------------------------------------
__global__ void init_bar(unsigned* bar) {
    bar[threadIdx.x] = 0;          // [0..255]: group counters (g*32)
    bar[threadIdx.x + 256] = 0;    // [320..327]: group XCD masks
}

// ---------------------------------------------------------------------------
// Per-group (32-block) barrier, relaxed spin. fast: same-XCD verified ->
// workgroup release + L1-only inv. safe: agent fences (any mapping).
// ---------------------------------------------------------------------------
__device__ __forceinline__ void group_barrier(unsigned* bar, int g,
                                              unsigned& tgt, int fast)
{
    __syncthreads();
    if (threadIdx.x == 0) {
        if (fast) __builtin_amdgcn_fence(__ATOMIC_RELEASE, "workgroup");
        else      __builtin_amdgcn_fence(__ATOMIC_RELEASE, "agent");
        __hip_atomic_fetch_add(bar + g * 32, 1u, __ATOMIC_RELAXED,
                               __HIP_MEMORY_SCOPE_AGENT);
        while (__hip_atomic_load(bar + g * 32, __ATOMIC_RELAXED,
                                 __HIP_MEMORY_SCOPE_AGENT) < tgt)
            __builtin_amdgcn_s_sleep(1);
        if (fast) {
            __builtin_amdgcn_fence(__ATOMIC_ACQUIRE, "workgroup");
            asm volatile("buffer_inv sc0" ::: "memory");   // vector L1 inv only
        } else {
            __builtin_amdgcn_fence(__ATOMIC_ACQUIRE, "agent");
        }
    }
    tgt += 32;
    __syncthreads();
}

// A-operand fragment load from global (MFMA 16x16x32 A layout:
// lane (li,q) holds A[row0+li][kstep*32 + q*8 .. +8]).
__device__ __forceinline__ short8 afrag(const ushort_t* __restrict__ p,
                                        int row, int K, int kpos)
{
    return *(const short8*)(p + (size_t)row * K + kpos);
}

// ---------------------------------------------------------------------------
// Persistent TRM kernel. grid 256 (1 block/CU, forced by 128KB LDS).
// Group g = bid&7 owns rows [g*128, g*128+128). slot = bid>>3 in 0..31.
// Block's fixed columns: GEMM1 cols slot*32..+32 (W1 slice in LDS, 64KB),
// GEMM2 cols slot*16..+16 (W2 slice in LDS, 64KB). Wave w handles rows
// w*32..+32 (2 m-subtiles). LDS weight layout [comp][n][chunk^(n&7)]*16B
// (chunk = k/8) -> uniform 8-segment spread for ds_read_b128.
// ---------------------------------------------------------------------------
__global__ __launch_bounds__(256, 1) void trm_persist(
    ushort_t* __restrict__ xs_hi, ushort_t* __restrict__ xs_lo,
    ushort_t* __restrict__ h1_hi, ushort_t* __restrict__ h1_lo,
    const ushort_t* __restrict__ W1h, const ushort_t* __restrict__ W1l,
    const ushort_t* __restrict__ W2h, const ushort_t* __restrict__ W2l,
    const float* __restrict__ bb1, const float* __restrict__ bb2,
    float* __restrict__ io, const float* __restrict__ inpf,
    float* __restrict__ latf, float* __restrict__ outf,
    const float* __restrict__ hw, const float* __restrict__ hb,
    float* __restrict__ logits, unsigned* bar)
{
    __shared__ __align__(16) unsigned char w1lds[65536];  // [comp][32n][64c]*16B
    __shared__ __align__(16) unsigned char w2lds[65536];  // [comp][16n][128c]*16B
    __shared__ int modeflag;

    const int tid = threadIdx.x;
    const int w = tid >> 6, lane = tid & 63;
    const int q = lane >> 4, li = lane & 15;
    const int bid = blockIdx.x;
    const int g = bid & 7;
    const int slot = bid >> 3;
    const int R0 = g * 128;
    const int c1 = slot * 32;       // GEMM1 col base
    const int c2 = slot * 16;       // GEMM2 col base

    // ---- preload weight slices into LDS (once per launch) ----
    for (int i = tid; i < 2 * 32 * 64; i += 256) {        // W1: 4096 chunks
        int comp = i >> 11;         // /2048
        int rem = i & 2047;
        int n = rem >> 6, c = rem & 63;
        const ushort_t* src = (comp ? W1l : W1h) + (size_t)(c1 + n) * 512 + c * 8;
        *(uint4*)(w1lds + comp * 32768 + (((n << 6) | (c ^ (n & 7))) << 4)) =
            *(const uint4*)src;
    }
    for (int i = tid; i < 2 * 16 * 128; i += 256) {       // W2: 4096 chunks
        int comp = i >> 11;
        int rem = i & 2047;
        int n = rem >> 7, c = rem & 127;
        const ushort_t* src = (comp ? W2l : W2h) + (size_t)(c2 + n) * 1024 + c * 8;
        *(uint4*)(w2lds + comp * 32768 + (((n << 7) | (c ^ (n & 7))) << 4)) =
            *(const uint4*)src;
    }

    // ---- mode probe: is this bid-group entirely on one physical XCD? ----
    if (tid == 0) {
        unsigned xcc;
        asm volatile("s_getreg_b32 %0, hwreg(HW_REG_XCC_ID)" : "=s"(xcc));
        __hip_atomic_fetch_or(bar + 320 + g, 1u << (xcc & 31u),
                              __ATOMIC_RELAXED, __HIP_MEMORY_SCOPE_AGENT);
        __hip_atomic_fetch_add(bar + g * 32, 1u, __ATOMIC_RELAXED,
                               __HIP_MEMORY_SCOPE_AGENT);
        while (__hip_atomic_load(bar + g * 32, __ATOMIC_RELAXED,
                                 __HIP_MEMORY_SCOPE_AGENT) < 32u)
            __builtin_amdgcn_s_sleep(1);
        __builtin_amdgcn_fence(__ATOMIC_ACQUIRE, "agent");
        unsigned msk = __hip_atomic_load(bar + 320 + g, __ATOMIC_RELAXED,
                                         __HIP_MEMORY_SCOPE_AGENT);
        modeflag = (__popc(msk) == 1) ? 1 : 0;
    }
    __syncthreads();
    const int fast = modeflag;
    unsigned tgt = 64;

    const int rowA = R0 + w * 32;   // wave's row base (2 subtiles of 16)
    // bias registers for this block's fixed columns
    float bias1[2];                 // bb1[c1 + tj*16 + li]
    bias1[0] = bb1[c1 + li];
    bias1[1] = bb1[c1 + 16 + li];
    float bias2 = bb2[c2 + li];

    for (int step = 0; step < 336; ++step) {              // 48 sup * 7
        // ==== GEMM1: h1[128 x 32cols] = relu(xs @ W1 + bb1), K=512 ====
        {
            f32x4 acc[2][2] = {};   // [ti][tj]
            short8 aF[3][2][2];     // ring [comp][ti]
#pragma unroll
            for (int p = 0; p < 2; ++p) {
                int kp = p * 32 + q * 8;
#pragma unroll
                for (int ti = 0; ti < 2; ++ti) {
                    aF[p][0][ti] = afrag(xs_hi, rowA + ti * 16 + li, 512, kp);
                    aF[p][1][ti] = afrag(xs_lo, rowA + ti * 16 + li, 512, kp);
                }
            }
#pragma unroll
            for (int s = 0; s < 16; ++s) {
                if (s + 2 < 16) {
                    int kp = (s + 2) * 32 + q * 8;
#pragma unroll
                    for (int ti = 0; ti < 2; ++ti) {
                        aF[(s + 2) % 3][0][ti] = afrag(xs_hi, rowA + ti * 16 + li, 512, kp);
                        aF[(s + 2) % 3][1][ti] = afrag(xs_lo, rowA + ti * 16 + li, 512, kp);
                    }
                }
                short8 bh[2], bl[2];
#pragma unroll
                for (int tj = 0; tj < 2; ++tj) {
                    int n = tj * 16 + li;
                    int sl = ((n << 6) | ((s * 4 + q) ^ (n & 7))) << 4;
                    bh[tj] = *(const short8*)(w1lds + sl);
                    bl[tj] = *(const short8*)(w1lds + 32768 + sl);
                }
                const short8* ah = aF[s % 3][0];
                const short8* al = aF[s % 3][1];
#pragma unroll
                for (int ti = 0; ti < 2; ++ti)
#pragma unroll
                    for (int tj = 0; tj < 2; ++tj) {
                        acc[ti][tj] = __builtin_amdgcn_mfma_f32_16x16x32_bf16(ah[ti], bh[tj], acc[ti][tj], 0, 0, 0);
                        acc[ti][tj] = __builtin_amdgcn_mfma_f32_16x16x32_bf16(ah[ti], bl[tj], acc[ti][tj], 0, 0, 0);
                        acc[ti][tj] = __builtin_amdgcn_mfma_f32_16x16x32_bf16(al[ti], bh[tj], acc[ti][tj], 0, 0, 0);
                        acc[ti][tj] = __builtin_amdgcn_mfma_f32_16x16x32_bf16(al[ti], bl[tj], acc[ti][tj], 0, 0, 0);
                    }
            }
            // epilogue: split h1 (C layout: col=lane&15, row=quad*4+reg)
#pragma unroll
            for (int ti = 0; ti < 2; ++ti)
#pragma unroll
                for (int tj = 0; tj < 2; ++tj) {
                    int colg = c1 + tj * 16 + li;
#pragma unroll
                    for (int rr = 0; rr < 4; ++rr) {
                        int rowg = rowA + ti * 16 + q * 4 + rr;
                        size_t idx = (size_t)rowg * 1024 + colg;
                        float v = fmaxf(acc[ti][tj][rr] + bias1[tj], 0.f);
                        split2(v, h1_hi[idx], h1_lo[idx]);
                    }
                }
        }
        group_barrier(bar, g, tgt, fast);

        // ==== GEMM2: xs'[128 x 16cols] = f(relu(h1 @ W2 + bb2)), K=1024 ====
        {
            int im = step % 7;
            int mode = (im < 5) ? 1 : ((im == 5) ? 2 : 3);
            f32x4 acc[2] = {};      // [ti]
            short8 aF[3][2][2];     // ring [comp][ti]
#pragma unroll
            for (int p = 0; p < 2; ++p) {
                int kp = p * 32 + q * 8;
#pragma unroll
                for (int ti = 0; ti < 2; ++ti) {
                    aF[p][0][ti] = afrag(h1_hi, rowA + ti * 16 + li, 1024, kp);
                    aF[p][1][ti] = afrag(h1_lo, rowA + ti * 16 + li, 1024, kp);
                }
            }
#pragma unroll
            for (int s = 0; s < 32; ++s) {
                if (s + 2 < 32) {
                    int kp = (s + 2) * 32 + q * 8;
#pragma unroll
                    for (int ti = 0; ti < 2; ++ti) {
                        aF[(s + 2) % 3][0][ti] = afrag(h1_hi, rowA + ti * 16 + li, 1024, kp);
                        aF[(s + 2) % 3][1][ti] = afrag(h1_lo, rowA + ti * 16 + li, 1024, kp);
                    }
                }
                int sl = ((li << 7) | ((s * 4 + q) ^ (li & 7))) << 4;
                short8 bh = *(const short8*)(w2lds + sl);
                short8 bl = *(const short8*)(w2lds + 32768 + sl);
                const short8* ah = aF[s % 3][0];
                const short8* al = aF[s % 3][1];
#pragma unroll
                for (int ti = 0; ti < 2; ++ti) {
                    acc[ti] = __builtin_amdgcn_mfma_f32_16x16x32_bf16(ah[ti], bh, acc[ti], 0, 0, 0);
                    acc[ti] = __builtin_amdgcn_mfma_f32_16x16x32_bf16(ah[ti], bl, acc[ti], 0, 0, 0);
                    acc[ti] = __builtin_amdgcn_mfma_f32_16x16x32_bf16(al[ti], bh, acc[ti], 0, 0, 0);
                    acc[ti] = __builtin_amdgcn_mfma_f32_16x16x32_bf16(al[ti], bl, acc[ti], 0, 0, 0);
                }
            }
            // epilogue with recursion-state chaining
            int colg = c2 + li;
#pragma unroll
            for (int ti = 0; ti < 2; ++ti)
#pragma unroll
                for (int rr = 0; rr < 4; ++rr) {
                    int rowg = rowA + ti * 16 + q * 4 + rr;
                    size_t idx = (size_t)rowg * 512 + colg;
                    float v = fmaxf(acc[ti][rr] + bias2, 0.f);
                    if (mode == 1) {
                        split2(io[idx] + v, xs_hi[idx], xs_lo[idx]);
                    } else if (mode == 2) {
                        split2(inpf[idx] + v, xs_hi[idx], xs_lo[idx]);
                        latf[idx] = v;
                    } else {
                        outf[idx] = v;
                        float t2 = inpf[idx] + v;
                        io[idx] = t2;
                        split2(t2 + latf[idx], xs_hi[idx], xs_lo[idx]);
                    }
                }
        }
        group_barrier(bar, g, tgt, fast);
    }

    // ---- head: logits rows [g*128, g*128+128) ----
    if (slot < 5) {
        int idx = slot * 256 + tid;                 // 0..1279 within group
        if (idx < 1280) {
            int rloc = idx / 10, j = idx % 10;
            int row = g * 128 + rloc;
            const float* r = outf + (size_t)row * 512;
            float s = hb[j];
            for (int k = 0; k < 512; ++k) s = fmaf(r[k], hw[k * 10 + j], s);
            logits[row * 10 + j] = s;
        }
    }
}

extern "C" void kernel_launch(void* const* d_in, const int* in_sizes, int n_in,
                              void* d_out, int out_size, void* d_ws, size_t ws_size,
                              hipStream_t stream)
{
    const float* raw   = (const float*)d_in[0];
    const float* out_e = (const float*)d_in[1];
    const float* lat_e = (const float*)d_in[2];
    const float* c1w = (const float*)d_in[3];
    const float* c1b = (const float*)d_in[4];
    const float* c2w = (const float*)d_in[5];
    const float* c2b = (const float*)d_in[6];
    const float* pw1 = (const float*)d_in[7];
    const float* pb1 = (const float*)d_in[8];
    const float* pw2 = (const float*)d_in[9];
    const float* pb2 = (const float*)d_in[10];
    const float* bw1 = (const float*)d_in[11];
    const float* bb1 = (const float*)d_in[12];
    const float* bw2 = (const float*)d_in[13];
    const float* bb2 = (const float*)d_in[14];
    const float* hw  = (const float*)d_in[15];
    const float* hb  = (const float*)d_in[16];
    // d_in[17]=Nsup(16), d_in[18]=n_latent(6): fixed, hard-coded.

    char* base = (char*)d_ws;
    float*    pool1  = (float*)   (base + 0);          // conv1 out (pre-backbone)
    ushort_t* h1_hi  = (ushort_t*)(base + 0);
    ushort_t* h1_lo  = (ushort_t*)(base + 2097152);
    ushort_t* xs_hi  = (ushort_t*)(base + 4194304);
    ushort_t* xs_lo  = (ushort_t*)(base + 5242880);
    float*    io     = (float*)   (base + 6291456);
    float*    latf   = (float*)   (base + 8388608);
    float*    h1f    = (float*)   (base + 0);          // proj1 out (pre-backbone)
    float*    h      = (float*)   (base + 12845056);   // conv2 out fp32
    float*    inpf   = (float*)   (base + 19267584);
    float*    outf   = (float*)   (base + 21364736);
    ushort_t* bW1t_h = (ushort_t*)(base + 23461888);   // [1024n][512k]
    ushort_t* bW1t_l = (ushort_t*)(base + 24510464);
    ushort_t* bW2t_h = (ushort_t*)(base + 25559040);   // [512n][1024k]
    ushort_t* bW2t_l = (ushort_t*)(base + 26607616);
    unsigned* bar    = (unsigned*)(base + 27656192);   // 2KB barrier lines

    // weight prep (every launch; ws is re-poisoned by harness)
    prep_wt<<<2048, 256, 0, stream>>>(bw1, bW1t_h, bW1t_l, 512, 1024);
    prep_wt<<<2048, 256, 0, stream>>>(bw2, bW2t_h, bW2t_l, 1024, 512);
    init_bar<<<1, 256, 0, stream>>>(bar);

    // fp32 prologue
    conv1_pool<<<3211264 / 256, 256, 0, stream>>>(raw, c1w, c1b, pool1);
    conv2_pool<<<1605632 / 256, 256, 0, stream>>>(pool1, c2w, c2b, h);
    gemm_f32<<<dim3(16, 16), 256, 0, stream>>>(h, pw1, pb1, h1f, 1024, 1024, 1568);
    gemm_f32<<<dim3(8, 16), 256, 0, stream>>>(h1f, pw2, pb2, inpf, 1024, 512, 1024);
    init_xs<<<2048, 256, 0, stream>>>(inpf, out_e, lat_e, io, xs_hi, xs_lo);

    // the whole recursion + head in ONE persistent kernel
    trm_persist<<<256, 256, 0, stream>>>(
        xs_hi, xs_lo, h1_hi, h1_lo, bW1t_h, bW1t_l, bW2t_h, bW2t_l,
        bb1, bb2, io, inpf, latf, outf, hw, hb, (float*)d_out, bar);
}

// Round 7
// 8439.984 us; speedup vs baseline: 4.1371x; 1.1316x over previous
//
#include <hip/hip_runtime.h>
#include <hip/hip_bf16.h>

// ---------------------------------------------------------------------------
// SimpleCNN / TRM forward. Round 7 = round 6 with the prefetch-ring aliasing
// bug fixed: ring depth 4 with distance 4 means (s+4)&3 == s&3, so the
// fragment MUST be copied out of the ring BEFORE the prefetch overwrites the
// slot (round 6 prefetched first -> consumed k+128-shifted A operands ->
// garbage recursion state). Consume-then-prefetch is the only change.
// Structure: persistent kernel, 512 thr (2 waves/SIMD), blocks self-organize
// into groups by PHYSICAL XCC_ID (exactly 32 blocks/XCD, 1 block/CU), weights
// LDS-resident in MFMA fragment order, barrier = workgroup fence + L1 inv.
// Math identical to rounds 2-5: split-bf16 MFMA, fp32 prologue.
// ---------------------------------------------------------------------------

typedef unsigned short ushort_t;
typedef __attribute__((ext_vector_type(8))) short short8;
typedef __attribute__((ext_vector_type(4))) float f32x4;

__device__ inline unsigned f2bf_rne(float v) {
    unsigned u = __float_as_uint(v);
    return (u + 0x7fffu + ((u >> 16) & 1u)) >> 16;
}
__device__ inline void split2(float v, ushort_t& h, ushort_t& l) {
    unsigned uh = f2bf_rne(v);
    h = (ushort_t)uh;
    float fh = __uint_as_float(uh << 16);
    l = (ushort_t)f2bf_rne(v - fh);
}

// ---------------- conv1 (1->16, 3x3 SAME, 28x28) + relu + maxpool2 ----------
__global__ __launch_bounds__(256) void conv1_pool(
    const float* __restrict__ in, const float* __restrict__ w,
    const float* __restrict__ bias, float* __restrict__ out)
{
    int idx = blockIdx.x * 256 + threadIdx.x;   // 1024*16*14*14
    int xo = idx % 14; int t = idx / 14;
    int yo = t % 14;  t /= 14;
    int oc = t % 16;  int b = t / 16;
    const float* ip = in + (size_t)b * 784;
    const float* wp = w + oc * 9;
    float win[4][4];
#pragma unroll
    for (int yy = 0; yy < 4; ++yy)
#pragma unroll
        for (int xx = 0; xx < 4; ++xx) {
            int y = 2 * yo + yy - 1, x = 2 * xo + xx - 1;
            win[yy][xx] = (y >= 0 && y < 28 && x >= 0 && x < 28) ? ip[y * 28 + x] : 0.f;
        }
    float bs = bias[oc];
    float m = -1e30f;
#pragma unroll
    for (int py = 0; py < 2; ++py)
#pragma unroll
        for (int px = 0; px < 2; ++px) {
            float s = bs;
#pragma unroll
            for (int dy = 0; dy < 3; ++dy)
#pragma unroll
                for (int dx = 0; dx < 3; ++dx)
                    s = fmaf(win[py + dy][px + dx], wp[dy * 3 + dx], s);
            m = fmaxf(m, s);
        }
    out[idx] = fmaxf(m, 0.f);
}

// ---------------- conv2 (16->32, 3x3 SAME, 14x14) + relu + maxpool2 ---------
__global__ __launch_bounds__(256) void conv2_pool(
    const float* __restrict__ in, const float* __restrict__ w,
    const float* __restrict__ bias, float* __restrict__ out)
{
    __shared__ float ws_[32 * 16 * 9];
    for (int i = threadIdx.x; i < 4608; i += 256) ws_[i] = w[i];
    __syncthreads();
    int idx = blockIdx.x * 256 + threadIdx.x;   // 1024*32*7*7
    int xo = idx % 7; int t = idx / 7;
    int yo = t % 7;  t /= 7;
    int oc = t % 32; int b = t / 32;
    const float* ip = in + (size_t)b * 16 * 196;
    float bs = bias[oc];
    float s00 = bs, s01 = bs, s10 = bs, s11 = bs;
    for (int ic = 0; ic < 16; ++ic) {
        const float* ipp = ip + ic * 196;
        float win[4][4];
#pragma unroll
        for (int yy = 0; yy < 4; ++yy)
#pragma unroll
            for (int xx = 0; xx < 4; ++xx) {
                int y = 2 * yo + yy - 1, x = 2 * xo + xx - 1;
                win[yy][xx] = (y >= 0 && y < 14 && x >= 0 && x < 14) ? ipp[y * 14 + x] : 0.f;
            }
        const float* wp = ws_ + (oc * 16 + ic) * 9;
#pragma unroll
        for (int dy = 0; dy < 3; ++dy)
#pragma unroll
            for (int dx = 0; dx < 3; ++dx) {
                float wv = wp[dy * 3 + dx];
                s00 = fmaf(win[0 + dy][0 + dx], wv, s00);
                s01 = fmaf(win[0 + dy][1 + dx], wv, s01);
                s10 = fmaf(win[1 + dy][0 + dx], wv, s10);
                s11 = fmaf(win[1 + dy][1 + dx], wv, s11);
            }
    }
    float m = fmaxf(fmaxf(s00, s01), fmaxf(s10, s11));
    out[idx] = fmaxf(m, 0.f);
}

// ---------------- fp32 tiled GEMM (prologue only: proj1, proj2) -------------
#define BMF 64
#define BNF 64
#define BKF 16

__global__ __launch_bounds__(256) void gemm_f32(
    const float* __restrict__ A0, const float* __restrict__ W,
    const float* __restrict__ bias, float* __restrict__ C,
    int M, int N, int K)
{
    __shared__ float As[BKF][BMF];
    __shared__ float Bs[BKF][BNF];
    const int tid = threadIdx.x;
    const int tx = tid % 16;
    const int ty = tid / 16;
    const int row0 = blockIdx.y * BMF;
    const int col0 = blockIdx.x * BNF;
    float acc[4][4] = {};
    const int ra = tid / 4;
    const int ca = 4 * (tid % 4);
    const int rb = tid / 16;
    const int cb = 4 * (tid % 16);
    for (int k0 = 0; k0 < K; k0 += BKF) {
        float4 v = *(const float4*)(A0 + (size_t)(row0 + ra) * K + k0 + ca);
        float4 bvec = *(const float4*)(W + (size_t)(k0 + rb) * N + col0 + cb);
        As[ca + 0][ra] = v.x;
        As[ca + 1][ra] = v.y;
        As[ca + 2][ra] = v.z;
        As[ca + 3][ra] = v.w;
        *(float4*)&Bs[rb][cb] = bvec;
        __syncthreads();
#pragma unroll
        for (int kk = 0; kk < BKF; ++kk) {
            float4 av = *(const float4*)&As[kk][ty * 4];
            float4 bv = *(const float4*)&Bs[kk][tx * 4];
            float a_[4] = {av.x, av.y, av.z, av.w};
            float b_[4] = {bv.x, bv.y, bv.z, bv.w};
#pragma unroll
            for (int i = 0; i < 4; ++i)
#pragma unroll
                for (int j = 0; j < 4; ++j)
                    acc[i][j] = fmaf(a_[i], b_[j], acc[i][j]);
        }
        __syncthreads();
    }
    float4 bv = *(const float4*)(bias + col0 + tx * 4);
    float bb[4] = {bv.x, bv.y, bv.z, bv.w};
#pragma unroll
    for (int i = 0; i < 4; ++i) {
        float4 o;
        o.x = fmaxf(acc[i][0] + bb[0], 0.f);
        o.y = fmaxf(acc[i][1] + bb[1], 0.f);
        o.z = fmaxf(acc[i][2] + bb[2], 0.f);
        o.w = fmaxf(acc[i][3] + bb[3], 0.f);
        *(float4*)(C + (size_t)(row0 + ty * 4 + i) * N + col0 + tx * 4) = o;
    }
}

// ---------------- weight prep: transpose + split ----------------------------
__global__ __launch_bounds__(256) void prep_wt(
    const float* __restrict__ w, ushort_t* __restrict__ th,
    ushort_t* __restrict__ tl, int K, int N)
{
    int idx = blockIdx.x * 256 + threadIdx.x;   // n*K + k
    int n = idx / K, k = idx % K;
    float v = w[(size_t)k * N + n];
    split2(v, th[idx], tl[idx]);
}

// ---------------- init: io = inp + out_e ; xs = split(io + lat_e) -----------
__global__ __launch_bounds__(256) void init_xs(
    const float* __restrict__ inpf, const float* __restrict__ oute,
    const float* __restrict__ late, float* __restrict__ io,
    ushort_t* __restrict__ xh, ushort_t* __restrict__ xl)
{
    int i = blockIdx.x * 256 + threadIdx.x;     // 1024*512
    float t = inpf[i] + oute[i];
    io[i] = t;
    split2(t + late[i], xh[i], xl[i]);
}

// ---------------- barrier init ---------------------------------------------
__global__ void init_bar(unsigned* bar) {
    bar[threadIdx.x] = 0;          // [0..255]: group barrier counters (g*32)
    bar[threadIdx.x + 256] = 0;    // [384+x*8]: XCD slot-claim counters
}

// ---------------------------------------------------------------------------
// Per-XCD-group (32-block) barrier. Groups are same-XCD BY CONSTRUCTION
// (self-organized via HW_REG_XCC_ID; 1 block/CU, 32 CUs/XCD -> exactly 32
// blocks/group). release = workgroup fence (write-through L1 -> data in the
// local L2 once vmcnt retires); acquire = workgroup fence + vector-L1 inv.
// Relaxed spin: no per-poll cache invalidates.
// ---------------------------------------------------------------------------
__device__ __forceinline__ void group_barrier(unsigned* bar, int g,
                                              unsigned& tgt)
{
    __syncthreads();
    if (threadIdx.x == 0) {
        __builtin_amdgcn_fence(__ATOMIC_RELEASE, "workgroup");
        __hip_atomic_fetch_add(bar + g * 32, 1u, __ATOMIC_RELAXED,
                               __HIP_MEMORY_SCOPE_AGENT);
        while (__hip_atomic_load(bar + g * 32, __ATOMIC_RELAXED,
                                 __HIP_MEMORY_SCOPE_AGENT) < tgt)
            __builtin_amdgcn_s_sleep(1);
        __builtin_amdgcn_fence(__ATOMIC_ACQUIRE, "workgroup");
        asm volatile("buffer_inv sc0" ::: "memory");   // vector L1 inv only
    }
    tgt += 32;
    __syncthreads();
}

// A-operand fragment load from global (MFMA 16x16x32 A layout:
// lane (li,q) holds A[row][q*8..q*8+8) at kpos offset).
__device__ __forceinline__ short8 afrag(const ushort_t* __restrict__ p,
                                        int row, int K, int kpos)
{
    return *(const short8*)(p + (size_t)row * K + kpos);
}

// ---------------------------------------------------------------------------
// Persistent TRM kernel. grid 256, 512 threads (8 waves, 2/SIMD), 1 block/CU
// (128KB LDS). Block self-assigns (g = physical XCD, slot = claim 0..31).
// Group g owns rows [g*128, g*128+128); wave w owns rows rowA = g*128+w*16.
// Block's fixed cols: GEMM1 c1 = slot*32 (W1 slice 64KB LDS), GEMM2
// c2 = slot*16 (W2 slice 64KB LDS). LDS weights in MFMA fragment order:
//   W1: [comp][s(0..15)][tj(0..1)][lane]*16B ; W2: [comp][s(0..31)][lane]*16B
// -> every ds_read_b128 is a wave-contiguous 1KB (zero bank conflicts).
// A-prefetch: depth-4 ring, distance 4 — consume-then-prefetch (the r6 fix).
// ---------------------------------------------------------------------------
__global__ __launch_bounds__(512, 2) void trm_persist(
    ushort_t* __restrict__ xs_hi, ushort_t* __restrict__ xs_lo,
    ushort_t* __restrict__ h1_hi, ushort_t* __restrict__ h1_lo,
    const ushort_t* __restrict__ W1h, const ushort_t* __restrict__ W1l,
    const ushort_t* __restrict__ W2h, const ushort_t* __restrict__ W2l,
    const float* __restrict__ bb1, const float* __restrict__ bb2,
    float* __restrict__ io, const float* __restrict__ inpf,
    float* __restrict__ latf, float* __restrict__ outf,
    const float* __restrict__ hw, const float* __restrict__ hb,
    float* __restrict__ logits, unsigned* bar)
{
    __shared__ __align__(16) unsigned char w1lds[65536];
    __shared__ __align__(16) unsigned char w2lds[65536];
    __shared__ int sh_gs;

    const int tid = threadIdx.x;
    const int w = tid >> 6, lane = tid & 63;
    const int q = lane >> 4, li = lane & 15;

    // ---- self-organize: group by PHYSICAL XCD, claim slot ----
    if (tid == 0) {
        unsigned xcc;
        asm volatile("s_getreg_b32 %0, hwreg(HW_REG_XCC_ID)" : "=s"(xcc));
        xcc &= 7u;
        unsigned s = __hip_atomic_fetch_add(bar + 384 + xcc * 8, 1u,
                                            __ATOMIC_RELAXED,
                                            __HIP_MEMORY_SCOPE_AGENT);
        sh_gs = (int)((xcc << 8) | (s & 31u));
    }
    __syncthreads();
    const int g = sh_gs >> 8;
    const int slot = sh_gs & 255;
    const int c1 = slot * 32;       // GEMM1 col base
    const int c2 = slot * 16;       // GEMM2 col base
    const int rowA = g * 128 + w * 16;

    // ---- preload weight slices into LDS in fragment order (once) ----
    for (int i = tid; i < 4096; i += 512) {               // W1: 2*32n*64c
        int comp = i >> 11;
        int rem = i & 2047;
        int n = rem >> 6, c = rem & 63;                   // n 0..31, c 0..63
        const ushort_t* src = (comp ? W1l : W1h) + (size_t)(c1 + n) * 512 + c * 8;
        int dst = ((((comp << 4) + (c >> 2)) * 2 + (n >> 4)) * 64 +
                   ((c & 3) * 16 + (n & 15))) * 16;
        *(uint4*)(w1lds + dst) = *(const uint4*)src;
    }
    for (int i = tid; i < 4096; i += 512) {               // W2: 2*16n*128c
        int comp = i >> 11;
        int rem = i & 2047;
        int n = rem >> 7, c = rem & 127;                  // n 0..15, c 0..127
        const ushort_t* src = (comp ? W2l : W2h) + (size_t)(c2 + n) * 1024 + c * 8;
        int dst = (((comp << 5) + (c >> 2)) * 64 + ((c & 3) * 16 + n)) * 16;
        *(uint4*)(w2lds + dst) = *(const uint4*)src;
    }
    __syncthreads();

    float bias1[2];
    bias1[0] = bb1[c1 + li];
    bias1[1] = bb1[c1 + 16 + li];
    float bias2 = bb2[c2 + li];
    unsigned tgt = 32;

    for (int step = 0; step < 336; ++step) {              // 48 sup * 7
        // ==== GEMM1: h1[16rows x 32cols] = relu(xs @ W1 + bb1), K=512 ====
        {
            f32x4 acc0 = {}, acc1 = {};
            short8 aF[4][2];                              // ring [slot][comp]
#pragma unroll
            for (int p = 0; p < 4; ++p) {
                int kp = p * 32 + q * 8;
                aF[p][0] = afrag(xs_hi, rowA + li, 512, kp);
                aF[p][1] = afrag(xs_lo, rowA + li, 512, kp);
            }
#pragma unroll
            for (int s = 0; s < 16; ++s) {
                // CONSUME first (copy out of ring)...
                short8 ah = aF[s & 3][0], al = aF[s & 3][1];
                // ...THEN prefetch into the now-free slot ((s+4)&3 == s&3)
                if (s + 4 < 16) {
                    int kp = (s + 4) * 32 + q * 8;
                    aF[(s + 4) & 3][0] = afrag(xs_hi, rowA + li, 512, kp);
                    aF[(s + 4) & 3][1] = afrag(xs_lo, rowA + li, 512, kp);
                }
                const int base = (s * 2 * 64 + lane) * 16;
                short8 bh0 = *(const short8*)(w1lds + base);
                short8 bh1 = *(const short8*)(w1lds + base + 1024);
                short8 bl0 = *(const short8*)(w1lds + 32768 + base);
                short8 bl1 = *(const short8*)(w1lds + 32768 + base + 1024);
                acc0 = __builtin_amdgcn_mfma_f32_16x16x32_bf16(ah, bh0, acc0, 0, 0, 0);
                acc0 = __builtin_amdgcn_mfma_f32_16x16x32_bf16(ah, bl0, acc0, 0, 0, 0);
                acc0 = __builtin_amdgcn_mfma_f32_16x16x32_bf16(al, bh0, acc0, 0, 0, 0);
                acc0 = __builtin_amdgcn_mfma_f32_16x16x32_bf16(al, bl0, acc0, 0, 0, 0);
                acc1 = __builtin_amdgcn_mfma_f32_16x16x32_bf16(ah, bh1, acc1, 0, 0, 0);
                acc1 = __builtin_amdgcn_mfma_f32_16x16x32_bf16(ah, bl1, acc1, 0, 0, 0);
                acc1 = __builtin_amdgcn_mfma_f32_16x16x32_bf16(al, bh1, acc1, 0, 0, 0);
                acc1 = __builtin_amdgcn_mfma_f32_16x16x32_bf16(al, bl1, acc1, 0, 0, 0);
            }
            // epilogue: split h1 (C layout: col=lane&15, row=quad*4+reg)
#pragma unroll
            for (int tj = 0; tj < 2; ++tj) {
                int colg = c1 + tj * 16 + li;
                float bv = bias1[tj];
#pragma unroll
                for (int rr = 0; rr < 4; ++rr) {
                    int rowg = rowA + q * 4 + rr;
                    size_t idx = (size_t)rowg * 1024 + colg;
                    float v = fmaxf((tj ? acc1[rr] : acc0[rr]) + bv, 0.f);
                    split2(v, h1_hi[idx], h1_lo[idx]);
                }
            }
        }
        group_barrier(bar, g, tgt);

        // ==== GEMM2: xs'[16rows x 16cols] = f(relu(h1 @ W2 + bb2)), K=1024 ====
        {
            int im = step % 7;
            int mode = (im < 5) ? 1 : ((im == 5) ? 2 : 3);
            f32x4 acc = {};
            short8 aF[4][2];
#pragma unroll
            for (int p = 0; p < 4; ++p) {
                int kp = p * 32 + q * 8;
                aF[p][0] = afrag(h1_hi, rowA + li, 1024, kp);
                aF[p][1] = afrag(h1_lo, rowA + li, 1024, kp);
            }
#pragma unroll
            for (int s = 0; s < 32; ++s) {
                short8 ah = aF[s & 3][0], al = aF[s & 3][1];   // consume first
                if (s + 4 < 32) {
                    int kp = (s + 4) * 32 + q * 8;
                    aF[(s + 4) & 3][0] = afrag(h1_hi, rowA + li, 1024, kp);
                    aF[(s + 4) & 3][1] = afrag(h1_lo, rowA + li, 1024, kp);
                }
                const int base = (s * 64 + lane) * 16;
                short8 bh = *(const short8*)(w2lds + base);
                short8 bl = *(const short8*)(w2lds + 32768 + base);
                acc = __builtin_amdgcn_mfma_f32_16x16x32_bf16(ah, bh, acc, 0, 0, 0);
                acc = __builtin_amdgcn_mfma_f32_16x16x32_bf16(ah, bl, acc, 0, 0, 0);
                acc = __builtin_amdgcn_mfma_f32_16x16x32_bf16(al, bh, acc, 0, 0, 0);
                acc = __builtin_amdgcn_mfma_f32_16x16x32_bf16(al, bl, acc, 0, 0, 0);
            }
            // epilogue with recursion-state chaining
            int colg = c2 + li;
#pragma unroll
            for (int rr = 0; rr < 4; ++rr) {
                int rowg = rowA + q * 4 + rr;
                size_t idx = (size_t)rowg * 512 + colg;
                float v = fmaxf(acc[rr] + bias2, 0.f);
                if (mode == 1) {
                    split2(io[idx] + v, xs_hi[idx], xs_lo[idx]);
                } else if (mode == 2) {
                    split2(inpf[idx] + v, xs_hi[idx], xs_lo[idx]);
                    latf[idx] = v;
                } else {
                    outf[idx] = v;
                    float t2 = inpf[idx] + v;
                    io[idx] = t2;
                    split2(t2 + latf[idx], xs_hi[idx], xs_lo[idx]);
                }
            }
        }
        group_barrier(bar, g, tgt);
    }

    // ---- head: logits rows [g*128, g*128+128), 1280 elems per group ----
    {
        int idx = slot * 512 + tid;
        if (idx < 1280) {
            int rloc = idx / 10, j = idx % 10;
            int row = g * 128 + rloc;
            const float* r = outf + (size_t)row * 512;
            float s = hb[j];
            for (int k = 0; k < 512; ++k) s = fmaf(r[k], hw[k * 10 + j], s);
            logits[row * 10 + j] = s;
        }
    }
}

extern "C" void kernel_launch(void* const* d_in, const int* in_sizes, int n_in,
                              void* d_out, int out_size, void* d_ws, size_t ws_size,
                              hipStream_t stream)
{
    const float* raw   = (const float*)d_in[0];
    const float* out_e = (const float*)d_in[1];
    const float* lat_e = (const float*)d_in[2];
    const float* c1w = (const float*)d_in[3];
    const float* c1b = (const float*)d_in[4];
    const float* c2w = (const float*)d_in[5];
    const float* c2b = (const float*)d_in[6];
    const float* pw1 = (const float*)d_in[7];
    const float* pb1 = (const float*)d_in[8];
    const float* pw2 = (const float*)d_in[9];
    const float* pb2 = (const float*)d_in[10];
    const float* bw1 = (const float*)d_in[11];
    const float* bb1 = (const float*)d_in[12];
    const float* bw2 = (const float*)d_in[13];
    const float* bb2 = (const float*)d_in[14];
    const float* hw  = (const float*)d_in[15];
    const float* hb  = (const float*)d_in[16];
    // d_in[17]=Nsup(16), d_in[18]=n_latent(6): fixed, hard-coded.

    char* base = (char*)d_ws;
    float*    pool1  = (float*)   (base + 0);          // conv1 out (pre-backbone)
    ushort_t* h1_hi  = (ushort_t*)(base + 0);
    ushort_t* h1_lo  = (ushort_t*)(base + 2097152);
    ushort_t* xs_hi  = (ushort_t*)(base + 4194304);
    ushort_t* xs_lo  = (ushort_t*)(base + 5242880);
    float*    io     = (float*)   (base + 6291456);
    float*    latf   = (float*)   (base + 8388608);
    float*    h1f    = (float*)   (base + 0);          // proj1 out (pre-backbone)
    float*    h      = (float*)   (base + 12845056);   // conv2 out fp32
    float*    inpf   = (float*)   (base + 19267584);
    float*    outf   = (float*)   (base + 21364736);
    ushort_t* bW1t_h = (ushort_t*)(base + 23461888);   // [1024n][512k]
    ushort_t* bW1t_l = (ushort_t*)(base + 24510464);
    ushort_t* bW2t_h = (ushort_t*)(base + 25559040);   // [512n][1024k]
    ushort_t* bW2t_l = (ushort_t*)(base + 26607616);
    unsigned* bar    = (unsigned*)(base + 27656192);   // 2KB barrier/claim

    // weight prep (every launch; ws is re-poisoned by harness)
    prep_wt<<<2048, 256, 0, stream>>>(bw1, bW1t_h, bW1t_l, 512, 1024);
    prep_wt<<<2048, 256, 0, stream>>>(bw2, bW2t_h, bW2t_l, 1024, 512);
    init_bar<<<1, 256, 0, stream>>>(bar);

    // fp32 prologue
    conv1_pool<<<3211264 / 256, 256, 0, stream>>>(raw, c1w, c1b, pool1);
    conv2_pool<<<1605632 / 256, 256, 0, stream>>>(pool1, c2w, c2b, h);
    gemm_f32<<<dim3(16, 16), 256, 0, stream>>>(h, pw1, pb1, h1f, 1024, 1024, 1568);
    gemm_f32<<<dim3(8, 16), 256, 0, stream>>>(h1f, pw2, pb2, inpf, 1024, 512, 1024);
    init_xs<<<2048, 256, 0, stream>>>(inpf, out_e, lat_e, io, xs_hi, xs_lo);

    // the whole recursion + head in ONE persistent kernel
    trm_persist<<<256, 512, 0, stream>>>(
        xs_hi, xs_lo, h1_hi, h1_lo, bW1t_h, bW1t_l, bW2t_h, bW2t_l,
        bb1, bb2, io, inpf, latf, outf, hw, hb, (float*)d_out, bar);
}